// Round 2
// baseline (5274.014 us; speedup 1.0000x reference)
//
#include <hip/hip_runtime.h>
#include <hip/hip_bf16.h>
#include <stdint.h>

// Problem constants
#define S_INPUT  1024
#define S_HIDDEN 2048
#define S_SEQ    256
#define S_BATCH  256

typedef __attribute__((ext_vector_type(8))) short bf16x8;   // 8 bf16 = 4 VGPRs
typedef __attribute__((ext_vector_type(4))) float f32x4;    // MFMA accumulator

__device__ __forceinline__ short f2bf(float f){
  union { float f; unsigned u; } v; v.f = f;
  unsigned r = v.u + 0x7fffu + ((v.u >> 16) & 1u);   // round-nearest-even
  return (short)(r >> 16);
}

// tanh via one v_exp_f32 + v_rcp_f32; exact at saturation (e->inf / e->0).
__device__ __forceinline__ float tanh_fast(float x){
  float e = __expf(2.0f * x);
  return 1.0f - 2.0f / (e + 1.0f);
}

// ---------------------------------------------------------------------------
// 64x64x(K) bf16 GEMM core, B^T layout: out[m][n] = sum_k A[m][k]*B[n][k].
// 256 threads = 4 waves in 2x2 grid, each wave owns a 32x32 sub-tile.
// 4-deep software pipeline: 4 LDS buffers per operand (4*8KB each = 64KB
// total), prefetch distance 3, counted s_waitcnt vmcnt(8) so prefetch loads
// stay in flight ACROSS barriers (raw s_barrier, NOT __syncthreads which
// drains vmcnt(0)). global_load_lds(16B) with linear LDS dest +
// inverse-swizzled global source + XOR-swizzled ds_read (kills the 32-way
// bank conflict of 128B-stride rows).
// ---------------------------------------------------------------------------
__device__ __forceinline__ void compute_tile(const char* as, const char* bs,
                                             int ra0, int ra1, int rb0, int rb1,
                                             int hi, f32x4 acc[2][2])
{
  #pragma unroll
  for (int kk = 0; kk < 2; ++kk){
    const int kb = kk*64 + hi*16;
    bf16x8 a0 = *(const bf16x8*)(as + ra0*128 + (kb ^ ((ra0 & 7) << 4)));
    bf16x8 a1 = *(const bf16x8*)(as + ra1*128 + (kb ^ ((ra1 & 7) << 4)));
    bf16x8 b0 = *(const bf16x8*)(bs + rb0*128 + (kb ^ ((rb0 & 7) << 4)));
    bf16x8 b1 = *(const bf16x8*)(bs + rb1*128 + (kb ^ ((rb1 & 7) << 4)));
    acc[0][0] = __builtin_amdgcn_mfma_f32_16x16x32_bf16(a0, b0, acc[0][0], 0, 0, 0);
    acc[0][1] = __builtin_amdgcn_mfma_f32_16x16x32_bf16(a0, b1, acc[0][1], 0, 0, 0);
    acc[1][0] = __builtin_amdgcn_mfma_f32_16x16x32_bf16(a1, b0, acc[1][0], 0, 0, 0);
    acc[1][1] = __builtin_amdgcn_mfma_f32_16x16x32_bf16(a1, b1, acc[1][1], 0, 0, 0);
  }
}

__device__ __forceinline__ void gemm_core(const short* __restrict__ A, int lda,
                                          const short* __restrict__ B, int ldb,
                                          int bm, int bn, int ktiles,
                                          f32x4 acc[2][2], char* As, char* Bs)
{
  const int tid  = threadIdx.x;
  const int lane = tid & 63;
  const int wid  = tid >> 6;
  const int wm   = (wid >> 1) & 1;
  const int wn   = wid & 1;
  const int r15  = lane & 15;
  const int hi   = lane >> 4;
  const int ra0 = wm*32 + r15,  ra1 = ra0 + 16;
  const int rb0 = wn*32 + r15,  rb1 = rb0 + 16;

  // Per-thread staging addresses (2 x 16B chunks per operand per thread).
  const int c0 = tid, c1 = tid + 256;
  const int r0 = c0 >> 3, r1 = c1 >> 3;
  const int e0 = ((((c0 & 7) << 4) ^ ((r0 & 7) << 4)) >> 1);  // element offset (inverse swizzle)
  const int e1 = ((((c1 & 7) << 4) ^ ((r1 & 7) << 4)) >> 1);
  const short* pa0 = A + (size_t)(bm + r0)*lda + e0;
  const short* pa1 = A + (size_t)(bm + r1)*lda + e1;
  const short* pb0 = B + (size_t)(bn + r0)*ldb + e0;
  const short* pb1 = B + (size_t)(bn + r1)*ldb + e1;
  char* la0 = As + c0*16;  char* la1 = As + c1*16;
  char* lb0 = Bs + c0*16;  char* lb1 = Bs + c1*16;

  // 4 vmcnt entries per STAGE per wave.
  #define STAGE(kt, s) do { \
    const int _ko = (kt)*64; const int _so = (s)*8192; \
    __builtin_amdgcn_global_load_lds((const __attribute__((address_space(1))) void*)(pa0 + _ko), \
                                     (__attribute__((address_space(3))) void*)(la0 + _so), 16, 0, 0); \
    __builtin_amdgcn_global_load_lds((const __attribute__((address_space(1))) void*)(pb0 + _ko), \
                                     (__attribute__((address_space(3))) void*)(lb0 + _so), 16, 0, 0); \
    __builtin_amdgcn_global_load_lds((const __attribute__((address_space(1))) void*)(pa1 + _ko), \
                                     (__attribute__((address_space(3))) void*)(la1 + _so), 16, 0, 0); \
    __builtin_amdgcn_global_load_lds((const __attribute__((address_space(1))) void*)(pb1 + _ko), \
                                     (__attribute__((address_space(3))) void*)(lb1 + _so), 16, 0, 0); \
  } while (0)

  STAGE(0, 0);
  if (ktiles > 1) STAGE(1, 1);
  if (ktiles > 2) STAGE(2, 2);

  for (int t = 0; t < ktiles; ++t){
    const int rem = ktiles - 1 - t;
    // Tile t's 4 loads are the oldest outstanding; stages t+1,t+2 (8 loads)
    // may stay in flight. Never drain to 0 in the main loop.
    if (rem >= 2)      asm volatile("s_waitcnt vmcnt(8)" ::: "memory");
    else if (rem == 1) asm volatile("s_waitcnt vmcnt(4)" ::: "memory");
    else               asm volatile("s_waitcnt vmcnt(0)" ::: "memory");
    asm volatile("s_barrier" ::: "memory");   // raw barrier: no vmcnt drain
    if (t + 3 < ktiles) STAGE(t + 3, (t + 3) & 3);
    const char* as = As + (t & 3)*8192;
    const char* bs = Bs + (t & 3)*8192;
    compute_tile(as, bs, ra0, ra1, rb0, rb1, hi, acc);
  }
  #undef STAGE
}

// C/D layout (m89-verified): within a 16x16 frag, col = lane&15, row = (lane>>4)*4 + i.
#define EPI_COORDS \
  const int lane = threadIdx.x & 63, wid = threadIdx.x >> 6; \
  const int wm = (wid>>1)&1, wn = wid&1, r15 = lane&15, hi = lane>>4;

#define GEMM_LDS __shared__ char As[4*8192], Bs[4*8192];

// ---------------------------------------------------------------------------
// Prologue kernels
// ---------------------------------------------------------------------------
__global__ __launch_bounds__(256) void k_build_wcat(const float* __restrict__ Wih,
                                                    const float* __restrict__ Whh,
                                                    short* __restrict__ Wcat)
{
  int j = blockIdx.x;
  for (int i = threadIdx.x; i < 3072; i += 256){
    float f = (i < 1024) ? Wih[(size_t)j*1024 + i] : Whh[(size_t)j*2048 + (i-1024)];
    Wcat[(size_t)j*3072 + i] = f2bf(f);
  }
}

__global__ __launch_bounds__(256) void k_build_acat(const float* __restrict__ x,
                                                    const float* __restrict__ h0,
                                                    short* __restrict__ Acat)
{
  int b = blockIdx.x;
  for (int i = threadIdx.x; i < 3072; i += 256){
    float f = (i < 1024) ? x[(size_t)b*1024 + i] : h0[(size_t)b*2048 + (i-1024)];
    Acat[(size_t)b*3072 + i] = f2bf(f);
  }
}

__global__ __launch_bounds__(256) void k_trans_wfc(const float* __restrict__ Wfc,
                                                   short* __restrict__ Wfcb,
                                                   short* __restrict__ WfcT)
{
  __shared__ float t[32][33];
  int i0 = blockIdx.x*32, k0 = blockIdx.y*32;
  int c = threadIdx.x & 31, r = threadIdx.x >> 5;   // r in 0..7
  #pragma unroll
  for (int rr = 0; rr < 4; ++rr){
    int i = i0 + r*4 + rr, k = k0 + c;
    float v = Wfc[(size_t)i*2048 + k];
    Wfcb[(size_t)i*2048 + k] = f2bf(v);
    t[r*4+rr][c] = v;
  }
  __syncthreads();
  #pragma unroll
  for (int rr = 0; rr < 4; ++rr){
    int k = k0 + r*4 + rr, i = i0 + c;
    WfcT[(size_t)k*1024 + i] = f2bf(t[c][r*4+rr]);
  }
}

__global__ __launch_bounds__(256) void k_cvec(const float* __restrict__ Wih,
                                              const float* __restrict__ bfc,
                                              const float* __restrict__ bih,
                                              const float* __restrict__ bhh,
                                              float* __restrict__ brnn,
                                              float* __restrict__ cvec)
{
  __shared__ float red[256];
  int j = blockIdx.x;
  float s = 0.f;
  for (int i = threadIdx.x; i < 1024; i += 256) s += Wih[(size_t)j*1024 + i]*bfc[i];
  red[threadIdx.x] = s; __syncthreads();
  for (int st = 128; st > 0; st >>= 1){
    if (threadIdx.x < st) red[threadIdx.x] += red[threadIdx.x+st];
    __syncthreads();
  }
  if (threadIdx.x == 0){
    float br = bih[j] + bhh[j];
    brnn[j] = br;
    cvec[j] = br + red[0];
  }
}

// Wcomb[j][k] = bf16( sum_i W_ih[j][i]*W_fc[i][k] + W_hh[j][k] )
__global__ __launch_bounds__(256) void k_wcomb(const short* __restrict__ Wcat,
                                               const short* __restrict__ WfcT,
                                               const float* __restrict__ Whh,
                                               short* __restrict__ Wcomb)
{
  GEMM_LDS
  f32x4 acc[2][2] = {};
  int bid = blockIdx.x;
  int xcd = bid & 7, j = bid >> 3;          // j 0..127
  int np = xcd*4 + (j & 3);                 // 0..31
  int mp = j >> 2;                          // 0..31
  int bm = mp*64, bn = np*64;
  gemm_core(Wcat, 3072, WfcT, 1024, bm, bn, 16, acc, As, Bs);
  EPI_COORDS
  #pragma unroll
  for (int mi = 0; mi < 2; ++mi)
    #pragma unroll
    for (int ni = 0; ni < 2; ++ni){
      int n = bn + wn*32 + ni*16 + r15;
      #pragma unroll
      for (int i = 0; i < 4; ++i){
        int m = bm + wm*32 + mi*16 + hi*4 + i;
        Wcomb[(size_t)m*2048 + n] = f2bf(acc[mi][ni][i] + Whh[(size_t)m*2048 + n]);
      }
    }
}

// h1 = tanh(Acat @ Wcat^T + brnn)
__global__ __launch_bounds__(256) void k_h1(const short* __restrict__ Acat,
                                            const short* __restrict__ Wcat,
                                            const float* __restrict__ brnn,
                                            short* __restrict__ h1)
{
  GEMM_LDS
  f32x4 acc[2][2] = {};
  int bid = blockIdx.x;
  int xcd = bid & 7, j = bid >> 3;          // j 0..15
  int np = xcd*4 + (j & 3);                 // 0..31
  int mp = j >> 2;                          // 0..3
  int bm = mp*64, bn = np*64;
  gemm_core(Acat, 3072, Wcat, 3072, bm, bn, 48, acc, As, Bs);
  EPI_COORDS
  #pragma unroll
  for (int mi = 0; mi < 2; ++mi)
    #pragma unroll
    for (int ni = 0; ni < 2; ++ni){
      int n = bn + wn*32 + ni*16 + r15;
      float cb = brnn[n];
      #pragma unroll
      for (int i = 0; i < 4; ++i){
        int m = bm + wm*32 + mi*16 + hi*4 + i;
        h1[(size_t)m*2048 + n] = f2bf(tanh_fast(acc[mi][ni][i] + cb));
      }
    }
}

// Fused step: blocks 0..127: h_{t+1} = tanh(h_t @ Wcomb^T + cvec)  (bf16 out)
//             blocks 128..191: out_{t-1} = h_t @ Wfc^T + b_fc      (f32 -> d_out)
// XCD-aware panel map: bid&7 = XCD; each XCD re-reads only its own 1MB Wcomb
// slice + 0.5MB Wfc slice (+1MB h) per step -> L2-resident.
__global__ __launch_bounds__(256) void k_step(const short* __restrict__ hcur,
                                              const short* __restrict__ Wcomb,
                                              const float* __restrict__ cvec,
                                              short* __restrict__ hnext,
                                              const short* __restrict__ Wfcb,
                                              const float* __restrict__ bfc,
                                              float* __restrict__ outp)
{
  GEMM_LDS
  f32x4 acc[2][2] = {};
  int bid = blockIdx.x;
  if (bid < 128){
    int xcd = bid & 7, j = bid >> 3;        // j 0..15
    int np = xcd*4 + (j & 3);               // 0..31
    int mp = j >> 2;                        // 0..3
    int bm = mp*64, bn = np*64;
    gemm_core(hcur, S_HIDDEN, Wcomb, S_HIDDEN, bm, bn, 32, acc, As, Bs);
    EPI_COORDS
    #pragma unroll
    for (int mi = 0; mi < 2; ++mi)
      #pragma unroll
      for (int ni = 0; ni < 2; ++ni){
        int n = bn + wn*32 + ni*16 + r15;
        float cb = cvec[n];
        #pragma unroll
        for (int i = 0; i < 4; ++i){
          int m = bm + wm*32 + mi*16 + hi*4 + i;
          hnext[(size_t)m*S_HIDDEN + n] = f2bf(tanh_fast(acc[mi][ni][i] + cb));
        }
      }
  } else {
    int b2 = bid - 128;
    int xcd = b2 & 7, j = b2 >> 3;          // j 0..7
    int np = xcd*2 + (j & 1);               // 0..15
    int mp = j >> 1;                        // 0..3
    int bm = mp*64, bn = np*64;
    gemm_core(hcur, S_HIDDEN, Wfcb, S_HIDDEN, bm, bn, 32, acc, As, Bs);
    EPI_COORDS
    #pragma unroll
    for (int mi = 0; mi < 2; ++mi)
      #pragma unroll
      for (int ni = 0; ni < 2; ++ni){
        int n = bn + wn*32 + ni*16 + r15;
        float cb = bfc[n];
        #pragma unroll
        for (int i = 0; i < 4; ++i){
          int m = bm + wm*32 + mi*16 + hi*4 + i;
          outp[(size_t)m*(S_SEQ*S_INPUT) + n] = acc[mi][ni][i] + cb;
        }
      }
  }
}

// out_255 = h_256 @ Wfc^T + b_fc
__global__ __launch_bounds__(256) void k_final(const short* __restrict__ hcur,
                                               const short* __restrict__ Wfcb,
                                               const float* __restrict__ bfc,
                                               float* __restrict__ outp)
{
  GEMM_LDS
  f32x4 acc[2][2] = {};
  int bid = blockIdx.x;
  int xcd = bid & 7, j = bid >> 3;          // j 0..7
  int np = xcd*2 + (j & 1);                 // 0..15
  int mp = j >> 1;                          // 0..3
  int bm = mp*64, bn = np*64;
  gemm_core(hcur, S_HIDDEN, Wfcb, S_HIDDEN, bm, bn, 32, acc, As, Bs);
  EPI_COORDS
  #pragma unroll
  for (int mi = 0; mi < 2; ++mi)
    #pragma unroll
    for (int ni = 0; ni < 2; ++ni){
      int n = bn + wn*32 + ni*16 + r15;
      float cb = bfc[n];
      #pragma unroll
      for (int i = 0; i < 4; ++i){
        int m = bm + wm*32 + mi*16 + hi*4 + i;
        outp[(size_t)m*(S_SEQ*S_INPUT) + n] = acc[mi][ni][i] + cb;
      }
    }
}

// ---------------------------------------------------------------------------
extern "C" void kernel_launch(void* const* d_in, const int* in_sizes, int n_in,
                              void* d_out, int out_size, void* d_ws, size_t ws_size,
                              hipStream_t stream)
{
  const float* x   = (const float*)d_in[0];   // (256,1,1024)
  const float* h0  = (const float*)d_in[1];   // (1,256,2048)
  const float* Wih = (const float*)d_in[2];   // (2048,1024)
  const float* Whh = (const float*)d_in[3];   // (2048,2048)
  const float* bih = (const float*)d_in[4];   // (2048)
  const float* bhh = (const float*)d_in[5];   // (2048)
  const float* Wfc = (const float*)d_in[6];   // (1024,2048)
  const float* bfc = (const float*)d_in[7];   // (1024)
  float* out = (float*)d_out;                 // (256,256,1024) f32

  char* ws = (char*)d_ws;
  size_t off = 0;
  auto alloc = [&](size_t bytes) -> void* {
    void* p = ws + off;
    off += (bytes + 255) & ~(size_t)255;
    return p;
  };
  short* Wcat = (short*)alloc((size_t)2048*3072*2);   // [W_ih | W_hh] bf16
  short* Acat = (short*)alloc((size_t)256*3072*2);    // [x0 | h0] bf16
  short* WfcT = (short*)alloc((size_t)2048*1024*2);   // W_fc^T bf16
  short* Wfcb = (short*)alloc((size_t)1024*2048*2);   // W_fc bf16
  short* Wcb  = (short*)alloc((size_t)2048*2048*2);   // Wcomb bf16
  short* hb0  = (short*)alloc((size_t)256*2048*2);
  short* hb1  = (short*)alloc((size_t)256*2048*2);
  float* brnn = (float*)alloc(2048*4);
  float* cvec = (float*)alloc(2048*4);
  (void)ws_size; (void)in_sizes; (void)n_in; (void)out_size;

  // Prologue
  k_build_wcat<<<2048, 256, 0, stream>>>(Wih, Whh, Wcat);
  k_build_acat<<<256, 256, 0, stream>>>(x, h0, Acat);
  k_trans_wfc<<<dim3(32, 64), 256, 0, stream>>>(Wfc, Wfcb, WfcT);
  k_cvec<<<2048, 256, 0, stream>>>(Wih, bfc, bih, bhh, brnn, cvec);
  k_wcomb<<<1024, 256, 0, stream>>>(Wcat, WfcT, Whh, Wcb);
  k_h1<<<128, 256, 0, stream>>>(Acat, Wcat, brnn, hb0);

  // Sequential steps: launch t computes h_{t+1} (task A) and out_{t-1} (task B)
  short* h[2] = { hb0, hb1 };
  int cur = 0;
  for (int t = 1; t <= 255; ++t){
    k_step<<<192, 256, 0, stream>>>(h[cur], Wcb, cvec, h[cur^1], Wfcb, bfc,
                                    out + (size_t)(t-1)*S_INPUT);
    cur ^= 1;
  }
  k_final<<<64, 256, 0, stream>>>(h[cur], Wfcb, bfc, out + (size_t)255*S_INPUT);
}